// Round 8
// baseline (149.913 us; speedup 1.0000x reference)
//
#include <hip/hip_runtime.h>
#include <math.h>

#define NPOS 4096
#define DCH  512
#define HD   32
#define NH   16
#define KW   9
#define DIL  3
#define PAD  12
#define TILE   256
#define NTILES (NPOS / TILE)        // 16
#define SPANT  (TILE + 2*PAD)       // 280 tokens staged per tile
#define ROWF4  (SPANT / 4)          // 70 float4 per channel row
#define PITCH  280                  // bf16 elems per LDS row
#define NUNIT  (HD * ROWF4 * 2)     // 4480 staging float4 units (k then v)
#define CSPL   4                    // channel-split lanes
#define CPT    (HD / CSPL)          // 8 channels per thread
#define TPT    4                    // tokens per thread
#define WSPAN  28                   // 4 tokens x 9 taps span 28 tokens
#define BLK    256

typedef unsigned short ushort_t;

// bank-spread permutation: logical channel ch -> physical LDS row
__device__ __forceinline__ int sigma(int ch) {
    return (ch >> 3) + 4 * (ch & 7);
}

__device__ __forceinline__ ushort_t f2bf(float f) {
    unsigned u = __float_as_uint(f);
    unsigned r = (u + 0x7FFFu + ((u >> 16) & 1u)) >> 16;   // RNE
    return (ushort_t)r;
}
__device__ __forceinline__ float bf2f(ushort_t h) {
    return __uint_as_float(((unsigned)h) << 16);
}

__global__ __launch_bounds__(BLK) void dilate_attn_kernel(
    const float* __restrict__ q,
    const float* __restrict__ k,
    const float* __restrict__ v,
    float* __restrict__ out)
{
    __shared__ __align__(16) ushort_t ks[HD * PITCH];   // 17920 B
    __shared__ __align__(16) ushort_t vs[HD * PITCH];   // 17920 B

    const int bh   = blockIdx.x >> 4;            // 0..63 (b*16+h)
    const int tile = blockIdx.x & (NTILES - 1);  // 0..15
    const int n0t  = tile * TILE;
    const int ws   = n0t - PAD;                  // staged span start
    const bool easy = (tile > 0) && (tile < NTILES - 1);

    const size_t cb = (size_t)bh * HD * NPOS;
    const float* kg = k + cb;
    const float* vg = v + cb;
    const float* qg = q + cb;

    // ------- Stage k,v as bf16 into LDS (coalesced f4 loads, permuted rows) -
    for (int p = threadIdx.x; p < NUNIT; p += BLK) {
        const bool isv = (p >= NUNIT / 2);
        int rem = isv ? (p - NUNIT / 2) : p;
        int row = rem / ROWF4;                   // logical channel 0..31
        int c4  = rem - row * ROWF4;             // float4 col 0..69
        int g0  = ws + c4 * 4;
        const float* src = (isv ? vg : kg) + (size_t)row * NPOS;
        float4 x;
        if (easy || (g0 >= 0 && g0 + 4 <= NPOS)) {
            x = *(const float4*)(src + g0);
        } else {                                  // tiles 0 / 15 only
            int i0 = min(max(g0 + 0, 0), NPOS - 1);
            int i1 = min(max(g0 + 1, 0), NPOS - 1);
            int i2 = min(max(g0 + 2, 0), NPOS - 1);
            int i3 = min(max(g0 + 3, 0), NPOS - 1);
            x = make_float4(src[i0], src[i1], src[i2], src[i3]);
        }
        ushort4 bx;
        bx.x = f2bf(x.x); bx.y = f2bf(x.y); bx.z = f2bf(x.z); bx.w = f2bf(x.w);
        ushort_t* dst = isv ? vs : ks;
        *(ushort4*)&dst[sigma(row) * PITCH + c4 * 4] = bx;   // 8B-aligned
    }

    // ------- q loads (fp32 float4, overlap staging latency) -----------------
    const int cs = threadIdx.x & (CSPL - 1);     // lane&3: channel octet slot
    const int lg = threadIdx.x >> 2;             // 0..63: token group in tile
    const int n0 = n0t + lg * TPT;               // first token this thread owns

    float4 qv[CPT];
#pragma unroll
    for (int i = 0; i < CPT; ++i)
        qv[i] = *(const float4*)(qg + (size_t)(cs * CPT + i) * NPOS + n0);

    __syncthreads();

    // ------- Pass 1: partial scores from LDS k (bf16) -----------------------
    float s[TPT][KW];
#pragma unroll
    for (int t = 0; t < TPT; ++t)
#pragma unroll
        for (int j = 0; j < KW; ++j) s[t][j] = 0.0f;

#pragma unroll
    for (int i = 0; i < CPT; ++i) {
        int prow = cs + 4 * i;                   // sigma(cs*8+i)
        const ushort4* wp = (const ushort4*)&ks[prow * PITCH + lg * TPT];
        float w[WSPAN];
#pragma unroll
        for (int u = 0; u < WSPAN / 4; ++u) {
            ushort4 x = wp[u];
            w[4*u]   = bf2f(x.x); w[4*u+1] = bf2f(x.y);
            w[4*u+2] = bf2f(x.z); w[4*u+3] = bf2f(x.w);
        }
        float qt[TPT] = {qv[i].x, qv[i].y, qv[i].z, qv[i].w};
#pragma unroll
        for (int t = 0; t < TPT; ++t)
#pragma unroll
            for (int j = 0; j < KW; ++j)
                s[t][j] = fmaf(qt[t], w[t + 3*j], s[t][j]);
    }

    // ------- Reduce partial scores across the 4 channel-split lanes ---------
#pragma unroll
    for (int t = 0; t < TPT; ++t)
#pragma unroll
        for (int j = 0; j < KW; ++j) {
            float x = s[t][j];
            x += __shfl_xor(x, 1);
            x += __shfl_xor(x, 2);
            s[t][j] = x;
        }

    // ------- Softmax per token ----------------------------------------------
    const float scale = 0.17677669529663687f;    // 32^-0.5
    if (easy) {                                  // interior: all taps valid
#pragma unroll
        for (int t = 0; t < TPT; ++t) {
            float m = -INFINITY;
#pragma unroll
            for (int j = 0; j < KW; ++j) {
                float x = s[t][j] * scale;
                s[t][j] = x;
                m = fmaxf(m, x);
            }
            float sum = 0.0f;
#pragma unroll
            for (int j = 0; j < KW; ++j) {
                float e = __expf(s[t][j] - m);
                s[t][j] = e;
                sum += e;
            }
            float inv = 1.0f / sum;
#pragma unroll
            for (int j = 0; j < KW; ++j) s[t][j] *= inv;
        }
    } else {                                     // edge tiles: mask invalid taps
#pragma unroll
        for (int t = 0; t < TPT; ++t) {
            float m = -INFINITY;
#pragma unroll
            for (int j = 0; j < KW; ++j) {
                float valid = ((unsigned)(n0 + t + 3*j - PAD) < NPOS) ? 1.0f : 0.0f;
                float x = s[t][j] * scale * valid;   // invalid logit = exactly 0
                s[t][j] = x;
                m = fmaxf(m, x);
            }
            float sum = 0.0f;
#pragma unroll
            for (int j = 0; j < KW; ++j) {
                float e = __expf(s[t][j] - m);
                s[t][j] = e;
                sum += e;
            }
            float inv = 1.0f / sum;
#pragma unroll
            for (int j = 0; j < KW; ++j) {
                float valid = ((unsigned)(n0 + t + 3*j - PAD) < NPOS) ? 1.0f : 0.0f;
                s[t][j] *= inv * valid;          // invalid taps contribute nothing
            }
        }
    }

    // ------- Pass 2: output from LDS v (bf16) -------------------------------
    float o[TPT][CPT];
#pragma unroll
    for (int t = 0; t < TPT; ++t)
#pragma unroll
        for (int i = 0; i < CPT; ++i) o[t][i] = 0.0f;

#pragma unroll
    for (int i = 0; i < CPT; ++i) {
        int prow = cs + 4 * i;
        const ushort4* wp = (const ushort4*)&vs[prow * PITCH + lg * TPT];
        float w[WSPAN];
#pragma unroll
        for (int u = 0; u < WSPAN / 4; ++u) {
            ushort4 x = wp[u];
            w[4*u]   = bf2f(x.x); w[4*u+1] = bf2f(x.y);
            w[4*u+2] = bf2f(x.z); w[4*u+3] = bf2f(x.w);
        }
#pragma unroll
        for (int t = 0; t < TPT; ++t)
#pragma unroll
            for (int j = 0; j < KW; ++j)
                o[t][i] = fmaf(s[t][j], w[t + 3*j], o[t][i]);
    }

    // ------- Store: two float4 per token ------------------------------------
    const int b  = bh >> 4;
    const int hh = bh & (NH - 1);
#pragma unroll
    for (int t = 0; t < TPT; ++t) {
        float* op = out + ((size_t)(b * NPOS + n0 + t)) * DCH + hh * HD + cs * CPT;
        *(float4*)op       = make_float4(o[t][0], o[t][1], o[t][2], o[t][3]);
        *(float4*)(op + 4) = make_float4(o[t][4], o[t][5], o[t][6], o[t][7]);
    }
}

extern "C" void kernel_launch(void* const* d_in, const int* in_sizes, int n_in,
                              void* d_out, int out_size, void* d_ws, size_t ws_size,
                              hipStream_t stream) {
    const float* q = (const float*)d_in[0];
    const float* k = (const float*)d_in[1];
    const float* v = (const float*)d_in[2];
    float* out = (float*)d_out;

    const int grid = 4 * NH * NTILES;   // 64 bh * 16 tiles = 1024 blocks
    hipLaunchKernelGGL(dilate_attn_kernel, dim3(grid), dim3(BLK), 0, stream,
                       q, k, v, out);
}